// Round 14
// baseline (20055.377 us; speedup 1.0000x reference)
//
#include <hip/hip_runtime.h>
#include <cmath>
#include <cstdint>
#include <cstddef>

#define BB   128
#define TT   512
#define INF  64
#define HH   1024
#define NG   4096
#define SS   64
#define NBLK 192
#define NTHR 512   // 8 waves

// LDS layout (byte offsets); total 163840 B = 160 KB
#define SWHI_B 0          // hi weights: 4 gates x 32 kc x 64 lanes x 16B = 131072
#define SLO_B  131072     // lo quad-buffer: 4 x 8192 B
#define LDS_BYTES 163840

typedef __attribute__((ext_vector_type(8))) short sh8;
typedef __attribute__((ext_vector_type(4))) float f32x4;

__device__ __forceinline__ float bf2f(unsigned short u) {
  unsigned int i = ((unsigned int)u) << 16;
  return __builtin_bit_cast(float, i);
}
__device__ __forceinline__ unsigned short f2bf(float f) {
  unsigned int u = __builtin_bit_cast(unsigned int, f);
  u += 0x7FFFu + ((u >> 16) & 1u);
  return (unsigned short)(u >> 16);
}
__device__ __forceinline__ float sigm(float x) { return 1.f / (1.f + __expf(-x)); }
__device__ __forceinline__ float tanh_f(float x) {
  x = fminf(15.f, fmaxf(-15.f, x));
  const float e = __expf(2.f * x);
  return (e - 1.f) / (e + 1.f);
}
__device__ __forceinline__ sh8 ld8(const unsigned short* p) { return *(const sh8*)p; }

// ---- CACHED asm accessors (L1/L2 path). Cross-block visibility is provided
// by the acquire/release fences in gbar (round-5-proven memory model): each
// XCD's L2 serves its 24 blocks one shared copy of the h-panels instead of
// every block pulling it from the coherence fabric (the round-9..13 sc
// scheme's 98 MB/iter bottleneck). asm keeps the counted-vmcnt exact. ----
__device__ __forceinline__ void ld8c(sh8& d, const unsigned short* p) {
  asm volatile("global_load_dwordx4 %0, %1, off" : "=v"(d) : "v"(p));
}
__device__ __forceinline__ void ldx4c(f32x4& d, const float* p) {
  asm volatile("global_load_dwordx4 %0, %1, off" : "=v"(d) : "v"(p));
}
__device__ __forceinline__ void stx4(float* p, f32x4 v) {
  asm volatile("global_store_dwordx4 %0, %1, off" :: "v"(p), "v"(v) : "memory");
}
__device__ __forceinline__ void st16(unsigned short* p, unsigned int v) {
  asm volatile("global_store_short %0, %1, off" :: "v"(p), "v"(v) : "memory");
}
// counted waits (rule #18: sched_barrier(0) right after stops MFMA hoisting)
__device__ __forceinline__ void waitvm(int n) {
  if (n == 15)      asm volatile("s_waitcnt vmcnt(15)" ::: "memory");
  else if (n == 10) asm volatile("s_waitcnt vmcnt(10)" ::: "memory");
  else if (n == 5)  asm volatile("s_waitcnt vmcnt(5)" ::: "memory");
  else              asm volatile("s_waitcnt vmcnt(0)" ::: "memory");
  __builtin_amdgcn_sched_barrier(0);
}

// Block barrier that does NOT drain vmcnt (prefetches stay in flight).
__device__ __forceinline__ void block_sync_lds() {
  asm volatile("s_waitcnt lgkmcnt(0)" ::: "memory");
  __builtin_amdgcn_s_barrier();
  asm volatile("" ::: "memory");
}

#if defined(__HIP_DEVICE_COMPILE__)
typedef __attribute__((ext_vector_type(8))) __bf16 bf8;
template <class T> T&& my_declval();
template <class V, class = void> struct mfma_takes { static constexpr bool value = false; };
template <class V>
struct mfma_takes<V, decltype((void)__builtin_amdgcn_mfma_f32_16x16x32_bf16(
                        my_declval<V>(), my_declval<V>(), my_declval<f32x4>(), 0, 0, 0))> {
  static constexpr bool value = true;
};
template <class V>
__device__ __forceinline__ f32x4 mfma_imp(V a, V b, f32x4 c) {
  return __builtin_amdgcn_mfma_f32_16x16x32_bf16(a, b, c, 0, 0, 0);
}
__device__ __forceinline__ f32x4 mfma_bf16(sh8 a, sh8 b, f32x4 c) {
  if constexpr (mfma_takes<sh8>::value) {
    return mfma_imp<sh8>(a, b, c);
  } else {
    return mfma_imp<bf8>(__builtin_bit_cast(bf8, a), __builtin_bit_cast(bf8, b), c);
  }
}
#else
__device__ __forceinline__ f32x4 mfma_bf16(sh8, sh8, f32x4 c) { return c; }
#endif

// ---------- preprocessing ----------
__global__ __launch_bounds__(256) void prep_weight(const float* __restrict__ W,
                                                   unsigned short* __restrict__ hi,
                                                   unsigned short* __restrict__ lo,
                                                   int lk) {
  const int K = 1 << lk;
  const int idx = blockIdx.x * 256 + threadIdx.x;
  if (idx >= (NG << lk)) return;
  const int n = idx >> lk;
  const int k = idx & (K - 1);
  const float v = W[idx];
  const unsigned short h = f2bf(v);
  const unsigned short l = f2bf(v - bf2f(h));
  const int nkch = K >> 5;
  const size_t o =
      ((((size_t)(n >> 4) * nkch + (k >> 5)) * 64) + (((k >> 3) & 3) * 16) + (n & 15)) * 8 +
      (k & 7);
  hi[o] = h;
  lo[o] = l;
}

__global__ __launch_bounds__(256) void prep_bias(const float* __restrict__ a,
                                                 const float* __restrict__ b,
                                                 float* __restrict__ o) {
  const int i = blockIdx.x * 256 + threadIdx.x;
  if (i < NG) o[i] = a[i] + b[i];
}

__global__ __launch_bounds__(256) void init_out(float* __restrict__ out_tmp,
                                                const float* __restrict__ fcb) {
  const int i = blockIdx.x * 256 + threadIdx.x;
  if (i < SS * BB) out_tmp[i] = fcb[0];
}

// ---------- persistent kernel ----------
struct KArgs {
  const float* x;
  const unsigned short *wih0_h, *wih0_l;
  const unsigned short *whh0e_h, *whh0e_l;
  const unsigned short *wih1e_h, *wih1e_l;
  const unsigned short *whh1e_h, *whh1e_l;
  const unsigned short *whh0d_h, *whh0d_l;
  const unsigned short *wih1d_h, *wih1d_l;
  const unsigned short *whh1d_h, *whh1d_l;
  const float *bias0e, *bias1e, *bias0d, *bias1d;
  const float *w0col, *fcw, *fcb;
  unsigned short *h0h0, *h0h1, *h0l0, *h0l1;
  unsigned short *h1h0, *h1h1, *h1l0, *h1l1;
  float *zb0, *zb1;
  float *out_tmp;
  float *outp;
  int *arrive;  // NBLK slots, 64B apart
};

// All-to-all grid barrier WITH acquire/release (round-5-proven model):
// per-wave vmcnt(0) drains asm stores into L2; tid0's release fence (wbl2)
// pushes the XCD's dirty lines to the coherence point before arrive; after
// all arrives are observed, tid0's acquire fence (inv L1/L2) guarantees
// fresh cached reads. Weights refetch from L3 (L3-resident) each iteration;
// h-panels are then L2-shared by all blocks of an XCD.
__device__ __forceinline__ void gbar(int* arrive, int it) {
  asm volatile("s_waitcnt vmcnt(0)" ::: "memory");
  __syncthreads();
  const int tid = threadIdx.x;
  if (tid == 0) {
    __threadfence();  // release: writeback L2
    __hip_atomic_store(&arrive[blockIdx.x * 16], it, __ATOMIC_RELAXED, __HIP_MEMORY_SCOPE_AGENT);
  }
  if (tid < NBLK) {
    while (__hip_atomic_load(&arrive[tid * 16], __ATOMIC_RELAXED, __HIP_MEMORY_SCOPE_AGENT) < it)
      __builtin_amdgcn_s_sleep(1);
  }
  __syncthreads();
  if (tid == 0) __threadfence();  // acquire: invalidate L1/L2
  __syncthreads();
  asm volatile("" ::: "memory");
}

// hi-weight slice (4 x 32KB contiguous) -> LDS (cached; read-only data)
__device__ __forceinline__ void load_whi(unsigned short* lds, const unsigned short* hi, int jt) {
#pragma unroll
  for (int g = 0; g < 4; ++g) {
    const uint4* src = (const uint4*)(hi + ((size_t)(g * 64 + jt) * 32) * 512);
    uint4* dst = (uint4*)((char*)lds + SWHI_B + g * 32768);
    for (int u = threadIdx.x; u < 2048; u += NTHR) dst[u] = src[u];
  }
}

__device__ __forceinline__ const unsigned short* lo_src(const unsigned short* glo, int jt,
                                                        int c, int f) {
  const int g = f >> 7, rem = f & 127, kcl = rem >> 6, l = rem & 63;
  const size_t u16 = ((size_t)((g * 64 + jt) * 32) + c * 2 + kcl) * 64 + l;
  return glo + u16 * 8;
}

// issue group G(c): 4 A-fragment loads (cached asm dwordx4) + 1
// global_load_lds (width 16, cached) staging this thread's 16B of the 8KB lo
// chunk into LDS buf c%4. 5 vmcnt ops per group.
__device__ __forceinline__ void issue_chunk(const unsigned short* arh, const unsigned short* arl,
                                            const unsigned short* glo, int jt, int c, int kg,
                                            int tid, int wid, unsigned short* lds,
                                            sh8 (&AH)[2], sh8 (&AL)[2]) {
#pragma unroll
  for (int kcl = 0; kcl < 2; ++kcl) {
    ld8c(AH[kcl], arh + c * 64 + kcl * 32 + kg * 8);
    ld8c(AL[kcl], arl + c * 64 + kcl * 32 + kg * 8);
  }
  __builtin_amdgcn_global_load_lds(
      (const void*)lo_src(glo, jt, c, tid),
      (void*)((char*)lds + SLO_B + (c % 4) * 8192 + wid * 1024), 16, 0, 0);
}

// one K-chunk: 24 MFMA; B-hi from resident LDS, B-lo from staged LDS buf c%4
__device__ __forceinline__ void compute_chunk(f32x4* acc, const unsigned short* lds, int c,
                                              int lane, const sh8 (&AH)[2], const sh8 (&AL)[2]) {
  __builtin_amdgcn_s_setprio(1);
#pragma unroll
  for (int kcl = 0; kcl < 2; ++kcl) {
    const int kc = c * 2 + kcl;
#pragma unroll
    for (int g = 0; g < 4; ++g) {
      const sh8 bH = ld8(lds + (g * 32 + kc) * 512 + lane * 8);
      const sh8 bL = ld8(lds + SLO_B / 2 + (c % 4) * 4096 + (g * 2 + kcl) * 512 + lane * 8);
      acc[g] = mfma_bf16(AH[kcl], bH, acc[g]);
      acc[g] = mfma_bf16(AL[kcl], bH, acc[g]);
      acc[g] = mfma_bf16(AH[kcl], bL, acc[g]);
    }
  }
  __builtin_amdgcn_s_setprio(0);
}

// acc += A(hi,lo)[128xHH] x B(jt-slice)^T. 4-slot pipeline, 3-group cover
// (covers post-invalidate L3 cold-miss latency): prologue issues G(0..3);
// each phase: compute c, wait G(c+1) retired, barrier, issue G(c+4).
__device__ __forceinline__ void gemm1024(f32x4* acc,
                                         const unsigned short* __restrict__ ah,
                                         const unsigned short* __restrict__ al,
                                         const unsigned short* __restrict__ glo,
                                         int jt, unsigned short* lds) {
  const int tid = threadIdx.x;
  const int lane = tid & 63, wid = tid >> 6;
  const int kg = lane >> 4;
  const int arow = wid * 16 + (lane & 15);
  const unsigned short* arh = ah + (size_t)arow * HH;
  const unsigned short* arl = al + (size_t)arow * HH;

  sh8 AH[4][2], AL[4][2];

  asm volatile("s_waitcnt vmcnt(0)" ::: "memory");  // clean vmcnt baseline
  issue_chunk(arh, arl, glo, jt, 0, kg, tid, wid, lds, AH[0], AL[0]);
  issue_chunk(arh, arl, glo, jt, 1, kg, tid, wid, lds, AH[1], AL[1]);
  issue_chunk(arh, arl, glo, jt, 2, kg, tid, wid, lds, AH[2], AL[2]);
  issue_chunk(arh, arl, glo, jt, 3, kg, tid, wid, lds, AH[3], AL[3]);
  waitvm(15);  // G(0) retired (G1..G3 in flight)
  block_sync_lds();

#pragma unroll
  for (int c = 0; c < 16; ++c) {
    compute_chunk(acc, lds, c, lane, AH[c % 4], AL[c % 4]);
    if (c < 15) {
      waitvm(c <= 12 ? 10 : (c == 13 ? 5 : 0));  // G(c+1) retired
      block_sync_lds();  // buf c%4 free for all waves; chunk c+1 visible
      if (c + 4 < 16)
        issue_chunk(arh, arl, glo, jt, c + 4, kg, tid, wid, lds, AH[c % 4], AL[c % 4]);
    }
  }
}

// encoder L0 extra: x(fp32) x Wih0, K=64; both weight halves L2-cached reads
__device__ __forceinline__ void gemm_x(f32x4* acc, const float* __restrict__ x, int t,
                                       const unsigned short* __restrict__ wxh,
                                       const unsigned short* __restrict__ wxl, int jt) {
  const int tid = threadIdx.x;
  const int lane = tid & 63, wid = tid >> 6;
  const int kg = lane >> 4;
  const int arow = wid * 16 + (lane & 15);
  const float* xr = x + (size_t)arow * (TT * INF) + t * INF;
#pragma unroll
  for (int kc2 = 0; kc2 < 2; ++kc2) {
    const int kb = kc2 * 32 + kg * 8;
    sh8 xh, xl;
#pragma unroll
    for (int e = 0; e < 8; ++e) {
      const float v = xr[kb + e];
      const unsigned short h = f2bf(v);
      xh[e] = (short)h;
      xl[e] = (short)f2bf(v - bf2f(h));
    }
#pragma unroll
    for (int g = 0; g < 4; ++g) {
      const size_t bo = (((size_t)(g * 64 + jt) * 2 + kc2) * 64 + lane) * 8;
      const sh8 bH = ld8(wxh + bo);
      const sh8 bL = ld8(wxl + bo);
      acc[g] = mfma_bf16(xh, bH, acc[g]);
      acc[g] = mfma_bf16(xl, bH, acc[g]);
      acc[g] = mfma_bf16(xh, bL, acc[g]);
    }
  }
}

__device__ __forceinline__ void store_z(f32x4* acc, float* zb, int jt) {
  const int tid = threadIdx.x;
  const int lane = tid & 63, wid = tid >> 6;
  const int col = lane & 15, kg = lane >> 4;
#pragma unroll
  for (int g = 0; g < 4; ++g) {
    const int row = g * HH + jt * 16 + col;
    const int bq = wid * 16 + kg * 4;
    stx4(zb + (size_t)row * BB + bq, acc[g]);
  }
}
__device__ __forceinline__ void add_z(f32x4* acc, const float* zb, int jt) {
  const int tid = threadIdx.x;
  const int lane = tid & 63, wid = tid >> 6;
  const int col = lane & 15, kg = lane >> 4;
  f32x4 t0, t1, t2, t3;
  const int bq = wid * 16 + kg * 4;
  ldx4c(t0, zb + (size_t)(0 * HH + jt * 16 + col) * BB + bq);
  ldx4c(t1, zb + (size_t)(1 * HH + jt * 16 + col) * BB + bq);
  ldx4c(t2, zb + (size_t)(2 * HH + jt * 16 + col) * BB + bq);
  ldx4c(t3, zb + (size_t)(3 * HH + jt * 16 + col) * BB + bq);
  asm volatile("s_waitcnt vmcnt(0)" ::: "memory");
  __builtin_amdgcn_sched_barrier(0);
  acc[0] += t0;
  acc[1] += t1;
  acc[2] += t2;
  acc[3] += t3;
}

// MODE: 0 plain, 1 rank-1 decoder input, 2 FC partial output
template <int MODE>
__device__ __forceinline__ void cellfin(f32x4* acc, float* creg,
                                        const float* __restrict__ bias, int jt,
                                        unsigned short* __restrict__ nhh,
                                        unsigned short* __restrict__ nhl,
                                        const float* w0g, const float* inp_vec, float fcwj,
                                        float* fc_out) {
  const int tid = threadIdx.x;
  const int lane = tid & 63, wid = tid >> 6;
  const int col = lane & 15, kg = lane >> 4;
  const int j = jt * 16 + col;
  const float b0 = bias[j], b1 = bias[HH + j], b2 = bias[2 * HH + j], b3 = bias[3 * HH + j];
#pragma unroll
  for (int r = 0; r < 4; ++r) {
    const int b = wid * 16 + kg * 4 + r;
    float zi = acc[0][r] + b0;
    float zf = acc[1][r] + b1;
    float zg = acc[2][r] + b2;
    float zo = acc[3][r] + b3;
    if constexpr (MODE == 1) {
      // atomic load: out_tmp is updated via L2-bypassing atomicAdd, and
      // init_out's dirty lines could otherwise serve stale cached values.
      const float ip = inp_vec
          ? __hip_atomic_load(inp_vec + b, __ATOMIC_RELAXED, __HIP_MEMORY_SCOPE_AGENT)
          : 0.f;
      zi += ip * w0g[0];
      zf += ip * w0g[1];
      zg += ip * w0g[2];
      zo += ip * w0g[3];
    }
    const float cn = sigm(zf) * creg[r] + sigm(zi) * tanh_f(zg);
    const float hn = sigm(zo) * tanh_f(cn);
    creg[r] = cn;
    const unsigned short hb = f2bf(hn);
    st16(nhh + (size_t)b * HH + j, hb);
    st16(nhl + (size_t)b * HH + j, f2bf(hn - bf2f(hb)));
    if constexpr (MODE == 2) {
      float cb = hn * fcwj;
      cb += __shfl_xor(cb, 1);
      cb += __shfl_xor(cb, 2);
      cb += __shfl_xor(cb, 4);
      cb += __shfl_xor(cb, 8);
      if (col == 0) atomicAdd(fc_out + b, cb);
    }
  }
}

__device__ __forceinline__ void zacc(f32x4* acc) {
#pragma unroll
  for (int g = 0; g < 4; ++g) acc[g] = f32x4{0.f, 0.f, 0.f, 0.f};
}

__global__ __launch_bounds__(NTHR, 2) void seq2seq_coop(KArgs a) {
  extern __shared__ unsigned short lds[];
  const int bid = blockIdx.x;
  const int role = bid >> 6;
  const int jt = bid & 63;
  const int tid = threadIdx.x;
  int bseq = 0;

  unsigned short* h0h[2] = {a.h0h0, a.h0h1};
  unsigned short* h0l[2] = {a.h0l0, a.h0l1};
  unsigned short* h1h[2] = {a.h1h0, a.h1h1};
  unsigned short* h1l[2] = {a.h1l0, a.h1l1};
  float* zb[2] = {a.zb0, a.zb1};

  if (role == 0) load_whi(lds, a.whh0e_h, jt);
  else if (role == 1) load_whi(lds, a.wih1e_h, jt);
  else load_whi(lds, a.whh1e_h, jt);
  __syncthreads();

  float creg[4] = {};

  // ---- encoder: software-pipelined roles, 1 grid barrier per iteration ----
  for (int i = 0; i < TT + 2; ++i) {
    if (role == 0) {
      if (i < TT) {
        f32x4 acc[4];
        zacc(acc);
        gemm1024(acc, h0h[(i + 1) & 1], h0l[(i + 1) & 1], a.whh0e_l, jt, lds);
        gemm_x(acc, a.x, i, a.wih0_h, a.wih0_l, jt);
        cellfin<0>(acc, creg, a.bias0e, jt, h0h[i & 1], h0l[i & 1], nullptr, nullptr, 0.f,
                   nullptr);
      }
    } else if (role == 1) {
      if (i >= 1 && i <= TT) {
        const int s = i - 1;
        f32x4 acc[4];
        zacc(acc);
        gemm1024(acc, h0h[s & 1], h0l[s & 1], a.wih1e_l, jt, lds);
        store_z(acc, zb[s & 1], jt);
      }
    } else {
      if (i >= 2) {
        const int s = i - 2;
        f32x4 acc[4];
        zacc(acc);
        gemm1024(acc, h1h[(s + 1) & 1], h1l[(s + 1) & 1], a.whh1e_l, jt, lds);
        add_z(acc, zb[s & 1], jt);
        cellfin<0>(acc, creg, a.bias1e, jt, h1h[s & 1], h1l[s & 1], nullptr, nullptr, 0.f,
                   nullptr);
      }
    }
    gbar(a.arrive, ++bseq);
  }

  // ---- decoder: reload LDS weights ----
  if (role == 0) load_whi(lds, a.whh0d_h, jt);
  else if (role == 1) load_whi(lds, a.wih1d_h, jt);
  else load_whi(lds, a.whh1d_h, jt);
  __syncthreads();

  float w0g[4] = {0.f, 0.f, 0.f, 0.f};
  float fcwj = 0.f;
  if (role == 0) {
    const int j = jt * 16 + (tid & 15);
    w0g[0] = a.w0col[j];
    w0g[1] = a.w0col[HH + j];
    w0g[2] = a.w0col[2 * HH + j];
    w0g[3] = a.w0col[3 * HH + j];
  }
  if (role == 2) fcwj = a.fcw[jt * 16 + (tid & 15)];

  for (int s = 0; s < SS; ++s) {
    f32x4 acc2[4];
    if (role == 2) {
      zacc(acc2);
      gemm1024(acc2, h1h[(s + 1) & 1], h1l[(s + 1) & 1], a.whh1d_l, jt, lds);
    }
    if (role == 0) {
      f32x4 acc[4];
      zacc(acc);
      gemm1024(acc, h0h[(s + 1) & 1], h0l[(s + 1) & 1], a.whh0d_l, jt, lds);
      cellfin<1>(acc, creg, a.bias0d, jt, h0h[s & 1], h0l[s & 1], w0g,
                 s ? a.out_tmp + (s - 1) * BB : nullptr, 0.f, nullptr);
    }
    gbar(a.arrive, ++bseq);
    if (role == 1) {
      f32x4 acc[4];
      zacc(acc);
      gemm1024(acc, h0h[s & 1], h0l[s & 1], a.wih1d_l, jt, lds);
      store_z(acc, zb[0], jt);
    }
    gbar(a.arrive, ++bseq);
    if (role == 2) {
      add_z(acc2, zb[0], jt);
      cellfin<2>(acc2, creg, a.bias1d, jt, h1h[s & 1], h1l[s & 1], nullptr, nullptr, fcwj,
                 a.out_tmp + s * BB);
    }
    gbar(a.arrive, ++bseq);
  }

  // ---- final: out_tmp (S,B) -> d_out (B,S) ----
  if (bid < 16) {
    const int gi = bid * NTHR + tid;  // gi = b*64 + s
    const int b = gi >> 6, s2 = gi & 63;
    a.outp[gi] =
        __hip_atomic_load(a.out_tmp + s2 * BB + b, __ATOMIC_RELAXED, __HIP_MEMORY_SCOPE_AGENT);
  }
}

extern "C" void kernel_launch(void* const* d_in, const int* in_sizes, int n_in,
                              void* d_out, int out_size, void* d_ws, size_t ws_size,
                              hipStream_t stream) {
  (void)in_sizes; (void)n_in; (void)out_size; (void)ws_size;
  const float* x     = (const float*)d_in[0];
  const float* eWih0 = (const float*)d_in[1];
  const float* eWhh0 = (const float*)d_in[2];
  const float* eBih0 = (const float*)d_in[3];
  const float* eBhh0 = (const float*)d_in[4];
  const float* eWih1 = (const float*)d_in[5];
  const float* eWhh1 = (const float*)d_in[6];
  const float* eBih1 = (const float*)d_in[7];
  const float* eBhh1 = (const float*)d_in[8];
  const float* dWih0 = (const float*)d_in[9];
  const float* dWhh0 = (const float*)d_in[10];
  const float* dBih0 = (const float*)d_in[11];
  const float* dBhh0 = (const float*)d_in[12];
  const float* dWih1 = (const float*)d_in[13];
  const float* dWhh1 = (const float*)d_in[14];
  const float* dBih1 = (const float*)d_in[15];
  const float* dBhh1 = (const float*)d_in[16];
  const float* fcW   = (const float*)d_in[17];
  const float* fcB   = (const float*)d_in[18];
  float* out = (float*)d_out;

  char* base = (char*)d_ws;
  size_t off = 0;
  auto alloc = [&](size_t bytes) -> void* {
    void* p = base + off;
    off = (off + bytes + 255) & ~(size_t)255;
    return p;
  };

  // zero-initialized block (one memset): h buffers + barrier flags
  unsigned short* h0h0 = (unsigned short*)alloc(BB * HH * 2);
  unsigned short* h0h1 = (unsigned short*)alloc(BB * HH * 2);
  unsigned short* h0l0 = (unsigned short*)alloc(BB * HH * 2);
  unsigned short* h0l1 = (unsigned short*)alloc(BB * HH * 2);
  unsigned short* h1h0 = (unsigned short*)alloc(BB * HH * 2);
  unsigned short* h1h1 = (unsigned short*)alloc(BB * HH * 2);
  unsigned short* h1l0 = (unsigned short*)alloc(BB * HH * 2);
  unsigned short* h1l1 = (unsigned short*)alloc(BB * HH * 2);
  int* bar = (int*)alloc(NBLK * 16 * sizeof(int));
  const size_t zbytes = off;

  float* zb0 = (float*)alloc((size_t)NG * BB * 4);
  float* zb1 = (float*)alloc((size_t)NG * BB * 4);
  float* out_tmp = (float*)alloc(SS * BB * 4);

  unsigned short* wih0_h = (unsigned short*)alloc((size_t)NG * INF * 2);
  unsigned short* wih0_l = (unsigned short*)alloc((size_t)NG * INF * 2);
  auto big = [&]() { return (unsigned short*)alloc((size_t)NG * HH * 2); };
  unsigned short *whh0e_h = big(), *whh0e_l = big();
  unsigned short *wih1e_h = big(), *wih1e_l = big();
  unsigned short *whh1e_h = big(), *whh1e_l = big();
  unsigned short *whh0d_h = big(), *whh0d_l = big();
  unsigned short *wih1d_h = big(), *wih1d_l = big();
  unsigned short *whh1d_h = big(), *whh1d_l = big();
  float* bias0e = (float*)alloc(NG * 4);
  float* bias1e = (float*)alloc(NG * 4);
  float* bias0d = (float*)alloc(NG * 4);
  float* bias1d = (float*)alloc(NG * 4);

  (void)hipMemsetAsync(base, 0, zbytes, stream);
  const int gb = (NG * HH + 255) / 256;
  prep_weight<<<gb, 256, 0, stream>>>(eWhh0, whh0e_h, whh0e_l, 10);
  prep_weight<<<gb, 256, 0, stream>>>(eWih1, wih1e_h, wih1e_l, 10);
  prep_weight<<<gb, 256, 0, stream>>>(eWhh1, whh1e_h, whh1e_l, 10);
  prep_weight<<<gb, 256, 0, stream>>>(dWhh0, whh0d_h, whh0d_l, 10);
  prep_weight<<<gb, 256, 0, stream>>>(dWih1, wih1d_h, wih1d_l, 10);
  prep_weight<<<gb, 256, 0, stream>>>(dWhh1, whh1d_h, whh1d_l, 10);
  prep_weight<<<(NG * INF + 255) / 256, 256, 0, stream>>>(eWih0, wih0_h, wih0_l, 6);
  const int gbias = (NG + 255) / 256;
  prep_bias<<<gbias, 256, 0, stream>>>(eBih0, eBhh0, bias0e);
  prep_bias<<<gbias, 256, 0, stream>>>(eBih1, eBhh1, bias1e);
  prep_bias<<<gbias, 256, 0, stream>>>(dBih0, dBhh0, bias0d);
  prep_bias<<<gbias, 256, 0, stream>>>(dBih1, dBhh1, bias1d);
  init_out<<<(SS * BB + 255) / 256, 256, 0, stream>>>(out_tmp, fcB);

  KArgs ka;
  ka.x = x;
  ka.wih0_h = wih0_h; ka.wih0_l = wih0_l;
  ka.whh0e_h = whh0e_h; ka.whh0e_l = whh0e_l;
  ka.wih1e_h = wih1e_h; ka.wih1e_l = wih1e_l;
  ka.whh1e_h = whh1e_h; ka.whh1e_l = whh1e_l;
  ka.whh0d_h = whh0d_h; ka.whh0d_l = whh0d_l;
  ka.wih1d_h = wih1d_h; ka.wih1d_l = wih1d_l;
  ka.whh1d_h = whh1d_h; ka.whh1d_l = whh1d_l;
  ka.bias0e = bias0e; ka.bias1e = bias1e; ka.bias0d = bias0d; ka.bias1d = bias1d;
  ka.w0col = dWih0; ka.fcw = fcW; ka.fcb = fcB;
  ka.h0h0 = h0h0; ka.h0h1 = h0h1; ka.h0l0 = h0l0; ka.h0l1 = h0l1;
  ka.h1h0 = h1h0; ka.h1h1 = h1h1; ka.h1l0 = h1l0; ka.h1l1 = h1l1;
  ka.zb0 = zb0; ka.zb1 = zb1;
  ka.out_tmp = out_tmp;
  ka.outp = out;
  ka.arrive = bar;

  (void)hipFuncSetAttribute((const void*)seq2seq_coop,
                            hipFuncAttributeMaxDynamicSharedMemorySize, LDS_BYTES);
  seq2seq_coop<<<dim3(NBLK), dim3(NTHR), LDS_BYTES, stream>>>(ka);
}

// Round 15
// 10408.615 us; speedup vs baseline: 1.9268x; 1.9268x over previous
//
#include <hip/hip_runtime.h>
#include <cmath>
#include <cstdint>
#include <cstddef>

#define BB   128
#define TT   512
#define INF  64
#define HH   1024
#define NG   4096
#define SS   64
#define NBLK 192
#define NTHR 512   // 8 waves

// LDS layout (byte offsets); total 155648 B = 152 KB
#define SWHI_B 0          // hi weights: 4 gates x 32 kc x 64 lanes x 16B = 131072
#define SLO_B  131072     // lo triple-buffer: 3 x 8192 B
#define LDS_BYTES 155648

#define LO_SCALE   2048.0f          // 2^11: keeps W-lo out of fp16 denormals
#define LO_UNSCALE 4.8828125e-4f    // 2^-11

typedef __attribute__((ext_vector_type(8))) short sh8;
typedef __attribute__((ext_vector_type(4))) float f32x4;

__device__ __forceinline__ float h2f(unsigned short u) {
  return (float)__builtin_bit_cast(_Float16, u);
}
__device__ __forceinline__ unsigned short f2h(float f) {
  return __builtin_bit_cast(unsigned short, (_Float16)f);
}
__device__ __forceinline__ float sigm(float x) { return 1.f / (1.f + __expf(-x)); }
__device__ __forceinline__ float tanh_f(float x) {
  x = fminf(15.f, fmaxf(-15.f, x));
  const float e = __expf(2.f * x);
  return (e - 1.f) / (e + 1.f);
}
__device__ __forceinline__ sh8 ld8(const unsigned short* p) { return *(const sh8*)p; }

// ---- asm accessors. sc0 sc1 = coherent (L3 coherence point, cross-XCD safe
// without fences) for mutable h/zb; plain cached for read-only weights. ----
__device__ __forceinline__ void ld8sc(sh8& d, const unsigned short* p) {
  asm volatile("global_load_dwordx4 %0, %1, off sc0 sc1" : "=v"(d) : "v"(p));
}
__device__ __forceinline__ void ldx4sc(f32x4& d, const float* p) {
  asm volatile("global_load_dwordx4 %0, %1, off sc0 sc1" : "=v"(d) : "v"(p));
}
__device__ __forceinline__ void stx4sc(float* p, f32x4 v) {
  asm volatile("global_store_dwordx4 %0, %1, off sc0 sc1" :: "v"(p), "v"(v) : "memory");
}
__device__ __forceinline__ void st16sc(unsigned short* p, unsigned int v) {
  asm volatile("global_store_short %0, %1, off sc0 sc1" :: "v"(p), "v"(v) : "memory");
}
// counted waits (rule #18: sched_barrier(0) right after stops MFMA hoisting)
__device__ __forceinline__ void waitvm(int n) {
  if (n == 6)       asm volatile("s_waitcnt vmcnt(6)" ::: "memory");
  else if (n == 3)  asm volatile("s_waitcnt vmcnt(3)" ::: "memory");
  else              asm volatile("s_waitcnt vmcnt(0)" ::: "memory");
  __builtin_amdgcn_sched_barrier(0);
}

// Block barrier that does NOT drain vmcnt (prefetches stay in flight).
__device__ __forceinline__ void block_sync_lds() {
  asm volatile("s_waitcnt lgkmcnt(0)" ::: "memory");
  __builtin_amdgcn_s_barrier();
  asm volatile("" ::: "memory");
}

#if defined(__HIP_DEVICE_COMPILE__)
typedef __attribute__((ext_vector_type(8))) _Float16 hf8;
template <class T> T&& my_declval();
template <class V, class = void> struct mfma_takes { static constexpr bool value = false; };
template <class V>
struct mfma_takes<V, decltype((void)__builtin_amdgcn_mfma_f32_16x16x32_f16(
                        my_declval<V>(), my_declval<V>(), my_declval<f32x4>(), 0, 0, 0))> {
  static constexpr bool value = true;
};
template <class V>
__device__ __forceinline__ f32x4 mfma_imp(V a, V b, f32x4 c) {
  return __builtin_amdgcn_mfma_f32_16x16x32_f16(a, b, c, 0, 0, 0);
}
__device__ __forceinline__ f32x4 mfma_f16(sh8 a, sh8 b, f32x4 c) {
  if constexpr (mfma_takes<sh8>::value) {
    return mfma_imp<sh8>(a, b, c);
  } else {
    return mfma_imp<hf8>(__builtin_bit_cast(hf8, a), __builtin_bit_cast(hf8, b), c);
  }
}
#else
__device__ __forceinline__ f32x4 mfma_f16(sh8, sh8, f32x4 c) { return c; }
#endif

// ---------- preprocessing ----------
// fp32 [NG][K] -> fp16 hi + (2^11-scaled) fp16 lo, MFMA B-fragment order.
__global__ __launch_bounds__(256) void prep_weight(const float* __restrict__ W,
                                                   unsigned short* __restrict__ hi,
                                                   unsigned short* __restrict__ lo,
                                                   int lk) {
  const int K = 1 << lk;
  const int idx = blockIdx.x * 256 + threadIdx.x;
  if (idx >= (NG << lk)) return;
  const int n = idx >> lk;
  const int k = idx & (K - 1);
  const float v = W[idx];
  const unsigned short h = f2h(v);
  const unsigned short l = f2h((v - h2f(h)) * LO_SCALE);
  const int nkch = K >> 5;
  const size_t o =
      ((((size_t)(n >> 4) * nkch + (k >> 5)) * 64) + (((k >> 3) & 3) * 16) + (n & 15)) * 8 +
      (k & 7);
  hi[o] = h;
  lo[o] = l;
}

__global__ __launch_bounds__(256) void prep_bias(const float* __restrict__ a,
                                                 const float* __restrict__ b,
                                                 float* __restrict__ o) {
  const int i = blockIdx.x * 256 + threadIdx.x;
  if (i < NG) o[i] = a[i] + b[i];
}

__global__ __launch_bounds__(256) void init_out(float* __restrict__ out_tmp,
                                                const float* __restrict__ fcb) {
  const int i = blockIdx.x * 256 + threadIdx.x;
  if (i < SS * BB) out_tmp[i] = fcb[0];
}

// ---------- persistent kernel ----------
struct KArgs {
  const float* x;
  const unsigned short *wih0_h, *wih0_l;
  const unsigned short *whh0e_h, *whh0e_l;
  const unsigned short *wih1e_h, *wih1e_l;
  const unsigned short *whh1e_h, *whh1e_l;
  const unsigned short *whh0d_h, *whh0d_l;
  const unsigned short *wih1d_h, *wih1d_l;
  const unsigned short *whh1d_h, *whh1d_l;
  const float *bias0e, *bias1e, *bias0d, *bias1d;
  const float *w0col, *fcw, *fcb;
  unsigned short *h00, *h01;  // layer-0 h ping-pong (fp16, single)
  unsigned short *h10, *h11;  // layer-1 h ping-pong
  float *zb0, *zb1;
  float *out_tmp;
  float *outp;
  int *arrive;  // NBLK slots, 64B apart
};

// All-to-all relaxed grid barrier (round-12-proven): data via sc0/sc1 ops
// drained by the explicit vmcnt(0); no acquire/release -> weights stay L2-warm.
__device__ __forceinline__ void gbar(int* arrive, int it) {
  asm volatile("s_waitcnt vmcnt(0)" ::: "memory");
  __syncthreads();
  const int tid = threadIdx.x;
  if (tid == 0)
    __hip_atomic_store(&arrive[blockIdx.x * 16], it, __ATOMIC_RELAXED, __HIP_MEMORY_SCOPE_AGENT);
  if (tid < NBLK) {
    while (__hip_atomic_load(&arrive[tid * 16], __ATOMIC_RELAXED, __HIP_MEMORY_SCOPE_AGENT) < it)
      __builtin_amdgcn_s_sleep(1);
  }
  __syncthreads();
  asm volatile("" ::: "memory");
}

// hi-weight slice (4 x 32KB contiguous) -> LDS (cached; read-only data)
__device__ __forceinline__ void load_whi(unsigned short* lds, const unsigned short* hi, int jt) {
#pragma unroll
  for (int g = 0; g < 4; ++g) {
    const uint4* src = (const uint4*)(hi + ((size_t)(g * 64 + jt) * 32) * 512);
    uint4* dst = (uint4*)((char*)lds + SWHI_B + g * 32768);
    for (int u = threadIdx.x; u < 2048; u += NTHR) dst[u] = src[u];
  }
}

__device__ __forceinline__ const unsigned short* lo_src(const unsigned short* glo, int jt,
                                                        int c, int f) {
  const int g = f >> 7, rem = f & 127, kcl = rem >> 6, l = rem & 63;
  const size_t u16 = ((size_t)((g * 64 + jt) * 32) + c * 2 + kcl) * 64 + l;
  return glo + u16 * 8;
}

// issue group G(c): 2 A loads (coherent, fp16 single) + 1 global_load_lds
// (width 16, cached) staging this thread's 16B of the 8KB lo chunk. 3 ops.
__device__ __forceinline__ void issue_chunk(const unsigned short* arh,
                                            const unsigned short* glo, int jt, int c, int kg,
                                            int tid, int wid, unsigned short* lds,
                                            sh8 (&AH)[2]) {
#pragma unroll
  for (int kcl = 0; kcl < 2; ++kcl)
    ld8sc(AH[kcl], arh + c * 64 + kcl * 32 + kg * 8);
  __builtin_amdgcn_global_load_lds(
      (const void*)lo_src(glo, jt, c, tid),
      (void*)((char*)lds + SLO_B + (c % 3) * 8192 + wid * 1024), 16, 0, 0);
}

// one K-chunk: 16 MFMA; B-hi -> acc, scaled B-lo -> accL (unscaled at end)
__device__ __forceinline__ void compute_chunk(f32x4* acc, f32x4* accL,
                                              const unsigned short* lds, int c, int lane,
                                              const sh8 (&AH)[2]) {
#pragma unroll
  for (int kcl = 0; kcl < 2; ++kcl) {
    const int kc = c * 2 + kcl;
#pragma unroll
    for (int g = 0; g < 4; ++g) {
      const sh8 bH = ld8(lds + (g * 32 + kc) * 512 + lane * 8);
      const sh8 bL = ld8(lds + SLO_B / 2 + (c % 3) * 4096 + (g * 2 + kcl) * 512 + lane * 8);
      acc[g] = mfma_f16(AH[kcl], bH, acc[g]);
      accL[g] = mfma_f16(AH[kcl], bL, accL[g]);
    }
  }
}

// acc += A(fp16)[128xHH] x B(jt-slice)^T. 3-slot pipeline, 2-phase cover.
__device__ __forceinline__ void gemm1024(f32x4* acc, f32x4* accL,
                                         const unsigned short* __restrict__ ah,
                                         const unsigned short* __restrict__ glo,
                                         int jt, unsigned short* lds) {
  const int tid = threadIdx.x;
  const int lane = tid & 63, wid = tid >> 6;
  const int kg = lane >> 4;
  const int arow = wid * 16 + (lane & 15);
  const unsigned short* arh = ah + (size_t)arow * HH;

  sh8 AH[3][2];

  asm volatile("s_waitcnt vmcnt(0)" ::: "memory");  // clean vmcnt baseline
  issue_chunk(arh, glo, jt, 0, kg, tid, wid, lds, AH[0]);
  issue_chunk(arh, glo, jt, 1, kg, tid, wid, lds, AH[1]);
  issue_chunk(arh, glo, jt, 2, kg, tid, wid, lds, AH[2]);
  waitvm(6);  // G(0)'s 3 ops retired (G1,G2 in flight)
  block_sync_lds();

#pragma unroll
  for (int c = 0; c < 16; ++c) {
    compute_chunk(acc, accL, lds, c, lane, AH[c % 3]);
    if (c < 15) {
      waitvm(c <= 13 ? 3 : 0);  // G(c+1) retired
      block_sync_lds();         // buf c%3 free for all waves; chunk c+1 visible
      if (c + 3 < 16)
        issue_chunk(arh, glo, jt, c + 3, kg, tid, wid, lds, AH[c % 3]);
    }
  }
}

__device__ __forceinline__ void combine(f32x4* acc, const f32x4* accL) {
#pragma unroll
  for (int g = 0; g < 4; ++g) acc[g] += accL[g] * LO_UNSCALE;
}

// encoder L0 extra: x(fp32) x Wih0, K=64; weights fp16 hi/lo, cached reads
__device__ __forceinline__ void gemm_x(f32x4* acc, f32x4* accL, const float* __restrict__ x,
                                       int t, const unsigned short* __restrict__ wxh,
                                       const unsigned short* __restrict__ wxl, int jt) {
  const int tid = threadIdx.x;
  const int lane = tid & 63, wid = tid >> 6;
  const int kg = lane >> 4;
  const int arow = wid * 16 + (lane & 15);
  const float* xr = x + (size_t)arow * (TT * INF) + t * INF;
#pragma unroll
  for (int kc2 = 0; kc2 < 2; ++kc2) {
    const int kb = kc2 * 32 + kg * 8;
    sh8 xh, xl;
#pragma unroll
    for (int e = 0; e < 8; ++e) {
      const float v = xr[kb + e];
      const unsigned short h = f2h(v);
      xh[e] = (short)h;
      xl[e] = (short)f2h((v - h2f(h)) * LO_SCALE);  // scaled residual
    }
#pragma unroll
    for (int g = 0; g < 4; ++g) {
      const size_t bo = (((size_t)(g * 64 + jt) * 2 + kc2) * 64 + lane) * 8;
      const sh8 bH = ld8(wxh + bo);
      const sh8 bL = ld8(wxl + bo);
      acc[g] = mfma_f16(xh, bH, acc[g]);
      accL[g] = mfma_f16(xl, bH, accL[g]);   // scaled x-lo
      accL[g] = mfma_f16(xh, bL, accL[g]);   // scaled W-lo
    }
  }
}

__device__ __forceinline__ void store_z(f32x4* acc, float* zb, int jt) {
  const int tid = threadIdx.x;
  const int lane = tid & 63, wid = tid >> 6;
  const int col = lane & 15, kg = lane >> 4;
#pragma unroll
  for (int g = 0; g < 4; ++g) {
    const int row = g * HH + jt * 16 + col;
    const int bq = wid * 16 + kg * 4;
    stx4sc(zb + (size_t)row * BB + bq, acc[g]);
  }
}
__device__ __forceinline__ void add_z(f32x4* acc, const float* zb, int jt) {
  const int tid = threadIdx.x;
  const int lane = tid & 63, wid = tid >> 6;
  const int col = lane & 15, kg = lane >> 4;
  f32x4 t0, t1, t2, t3;
  const int bq = wid * 16 + kg * 4;
  ldx4sc(t0, zb + (size_t)(0 * HH + jt * 16 + col) * BB + bq);
  ldx4sc(t1, zb + (size_t)(1 * HH + jt * 16 + col) * BB + bq);
  ldx4sc(t2, zb + (size_t)(2 * HH + jt * 16 + col) * BB + bq);
  ldx4sc(t3, zb + (size_t)(3 * HH + jt * 16 + col) * BB + bq);
  asm volatile("s_waitcnt vmcnt(0)" ::: "memory");
  __builtin_amdgcn_sched_barrier(0);
  acc[0] += t0;
  acc[1] += t1;
  acc[2] += t2;
  acc[3] += t3;
}

// MODE: 0 plain, 1 rank-1 decoder input, 2 FC partial output
template <int MODE>
__device__ __forceinline__ void cellfin(f32x4* acc, float* creg,
                                        const float* __restrict__ bias, int jt,
                                        unsigned short* __restrict__ nh,
                                        const float* w0g, const float* inp_vec, float fcwj,
                                        float* fc_out) {
  const int tid = threadIdx.x;
  const int lane = tid & 63, wid = tid >> 6;
  const int col = lane & 15, kg = lane >> 4;
  const int j = jt * 16 + col;
  const float b0 = bias[j], b1 = bias[HH + j], b2 = bias[2 * HH + j], b3 = bias[3 * HH + j];
#pragma unroll
  for (int r = 0; r < 4; ++r) {
    const int b = wid * 16 + kg * 4 + r;
    float zi = acc[0][r] + b0;
    float zf = acc[1][r] + b1;
    float zg = acc[2][r] + b2;
    float zo = acc[3][r] + b3;
    if constexpr (MODE == 1) {
      const float ip = inp_vec
          ? __hip_atomic_load(inp_vec + b, __ATOMIC_RELAXED, __HIP_MEMORY_SCOPE_AGENT)
          : 0.f;
      zi += ip * w0g[0];
      zf += ip * w0g[1];
      zg += ip * w0g[2];
      zo += ip * w0g[3];
    }
    const float cn = sigm(zf) * creg[r] + sigm(zi) * tanh_f(zg);
    const float hn = sigm(zo) * tanh_f(cn);
    creg[r] = cn;
    st16sc(nh + (size_t)b * HH + j, f2h(hn));  // h stored as single fp16
    if constexpr (MODE == 2) {
      float cb = hn * fcwj;
      cb += __shfl_xor(cb, 1);
      cb += __shfl_xor(cb, 2);
      cb += __shfl_xor(cb, 4);
      cb += __shfl_xor(cb, 8);
      if (col == 0) atomicAdd(fc_out + b, cb);
    }
  }
}

__device__ __forceinline__ void zacc(f32x4* acc) {
#pragma unroll
  for (int g = 0; g < 4; ++g) acc[g] = f32x4{0.f, 0.f, 0.f, 0.f};
}

__global__ __launch_bounds__(NTHR, 2) void seq2seq_coop(KArgs a) {
  extern __shared__ unsigned short lds[];
  const int bid = blockIdx.x;
  const int role = bid >> 6;
  const int jt = bid & 63;
  const int tid = threadIdx.x;
  int bseq = 0;

  unsigned short* h0[2] = {a.h00, a.h01};
  unsigned short* h1[2] = {a.h10, a.h11};
  float* zb[2] = {a.zb0, a.zb1};

  if (role == 0) load_whi(lds, a.whh0e_h, jt);
  else if (role == 1) load_whi(lds, a.wih1e_h, jt);
  else load_whi(lds, a.whh1e_h, jt);
  __syncthreads();

  float creg[4] = {};

  // ---- encoder: software-pipelined roles, 1 grid barrier per iteration ----
  for (int i = 0; i < TT + 2; ++i) {
    if (role == 0) {
      if (i < TT) {
        f32x4 acc[4], accL[4];
        zacc(acc);
        zacc(accL);
        gemm1024(acc, accL, h0[(i + 1) & 1], a.whh0e_l, jt, lds);
        gemm_x(acc, accL, a.x, i, a.wih0_h, a.wih0_l, jt);
        combine(acc, accL);
        cellfin<0>(acc, creg, a.bias0e, jt, h0[i & 1], nullptr, nullptr, 0.f, nullptr);
      }
    } else if (role == 1) {
      if (i >= 1 && i <= TT) {
        const int s = i - 1;
        f32x4 acc[4], accL[4];
        zacc(acc);
        zacc(accL);
        gemm1024(acc, accL, h0[s & 1], a.wih1e_l, jt, lds);
        combine(acc, accL);
        store_z(acc, zb[s & 1], jt);
      }
    } else {
      if (i >= 2) {
        const int s = i - 2;
        f32x4 acc[4], accL[4];
        zacc(acc);
        zacc(accL);
        gemm1024(acc, accL, h1[(s + 1) & 1], a.whh1e_l, jt, lds);
        combine(acc, accL);
        add_z(acc, zb[s & 1], jt);
        cellfin<0>(acc, creg, a.bias1e, jt, h1[s & 1], nullptr, nullptr, 0.f, nullptr);
      }
    }
    gbar(a.arrive, ++bseq);
  }

  // ---- decoder: reload LDS weights ----
  if (role == 0) load_whi(lds, a.whh0d_h, jt);
  else if (role == 1) load_whi(lds, a.wih1d_h, jt);
  else load_whi(lds, a.whh1d_h, jt);
  __syncthreads();

  float w0g[4] = {0.f, 0.f, 0.f, 0.f};
  float fcwj = 0.f;
  if (role == 0) {
    const int j = jt * 16 + (tid & 15);
    w0g[0] = a.w0col[j];
    w0g[1] = a.w0col[HH + j];
    w0g[2] = a.w0col[2 * HH + j];
    w0g[3] = a.w0col[3 * HH + j];
  }
  if (role == 2) fcwj = a.fcw[jt * 16 + (tid & 15)];

  for (int s = 0; s < SS; ++s) {
    f32x4 acc2[4], accL2[4];
    if (role == 2) {
      zacc(acc2);
      zacc(accL2);
      gemm1024(acc2, accL2, h1[(s + 1) & 1], a.whh1d_l, jt, lds);
      combine(acc2, accL2);
    }
    if (role == 0) {
      f32x4 acc[4], accL[4];
      zacc(acc);
      zacc(accL);
      gemm1024(acc, accL, h0[(s + 1) & 1], a.whh0d_l, jt, lds);
      combine(acc, accL);
      cellfin<1>(acc, creg, a.bias0d, jt, h0[s & 1], w0g,
                 s ? a.out_tmp + (s - 1) * BB : nullptr, 0.f, nullptr);
    }
    gbar(a.arrive, ++bseq);
    if (role == 1) {
      f32x4 acc[4], accL[4];
      zacc(acc);
      zacc(accL);
      gemm1024(acc, accL, h0[s & 1], a.wih1d_l, jt, lds);
      combine(acc, accL);
      store_z(acc, zb[0], jt);
    }
    gbar(a.arrive, ++bseq);
    if (role == 2) {
      add_z(acc2, zb[0], jt);
      cellfin<2>(acc2, creg, a.bias1d, jt, h1[s & 1], nullptr, nullptr, fcwj,
                 a.out_tmp + s * BB);
    }
    gbar(a.arrive, ++bseq);
  }

  // ---- final: out_tmp (S,B) -> d_out (B,S) ----
  if (bid < 16) {
    const int gi = bid * NTHR + tid;  // gi = b*64 + s
    const int b = gi >> 6, s2 = gi & 63;
    a.outp[gi] =
        __hip_atomic_load(a.out_tmp + s2 * BB + b, __ATOMIC_RELAXED, __HIP_MEMORY_SCOPE_AGENT);
  }
}

extern "C" void kernel_launch(void* const* d_in, const int* in_sizes, int n_in,
                              void* d_out, int out_size, void* d_ws, size_t ws_size,
                              hipStream_t stream) {
  (void)in_sizes; (void)n_in; (void)out_size; (void)ws_size;
  const float* x     = (const float*)d_in[0];
  const float* eWih0 = (const float*)d_in[1];
  const float* eWhh0 = (const float*)d_in[2];
  const float* eBih0 = (const float*)d_in[3];
  const float* eBhh0 = (const float*)d_in[4];
  const float* eWih1 = (const float*)d_in[5];
  const float* eWhh1 = (const float*)d_in[6];
  const float* eBih1 = (const float*)d_in[7];
  const float* eBhh1 = (const float*)d_in[8];
  const float* dWih0 = (const float*)d_in[9];
  const float* dWhh0 = (const float*)d_in[10];
  const float* dBih0 = (const float*)d_in[11];
  const float* dBhh0 = (const float*)d_in[12];
  const float* dWih1 = (const float*)d_in[13];
  const float* dWhh1 = (const float*)d_in[14];
  const float* dBih1 = (const float*)d_in[15];
  const float* dBhh1 = (const float*)d_in[16];
  const float* fcW   = (const float*)d_in[17];
  const float* fcB   = (const float*)d_in[18];
  float* out = (float*)d_out;

  char* base = (char*)d_ws;
  size_t off = 0;
  auto alloc = [&](size_t bytes) -> void* {
    void* p = base + off;
    off = (off + bytes + 255) & ~(size_t)255;
    return p;
  };

  // zero-initialized block (one memset): h buffers + barrier flags
  unsigned short* h00 = (unsigned short*)alloc(BB * HH * 2);
  unsigned short* h01 = (unsigned short*)alloc(BB * HH * 2);
  unsigned short* h10 = (unsigned short*)alloc(BB * HH * 2);
  unsigned short* h11 = (unsigned short*)alloc(BB * HH * 2);
  int* bar = (int*)alloc(NBLK * 16 * sizeof(int));
  const size_t zbytes = off;

  float* zb0 = (float*)alloc((size_t)NG * BB * 4);
  float* zb1 = (float*)alloc((size_t)NG * BB * 4);
  float* out_tmp = (float*)alloc(SS * BB * 4);

  unsigned short* wih0_h = (unsigned short*)alloc((size_t)NG * INF * 2);
  unsigned short* wih0_l = (unsigned short*)alloc((size_t)NG * INF * 2);
  auto big = [&]() { return (unsigned short*)alloc((size_t)NG * HH * 2); };
  unsigned short *whh0e_h = big(), *whh0e_l = big();
  unsigned short *wih1e_h = big(), *wih1e_l = big();
  unsigned short *whh1e_h = big(), *whh1e_l = big();
  unsigned short *whh0d_h = big(), *whh0d_l = big();
  unsigned short *wih1d_h = big(), *wih1d_l = big();
  unsigned short *whh1d_h = big(), *whh1d_l = big();
  float* bias0e = (float*)alloc(NG * 4);
  float* bias1e = (float*)alloc(NG * 4);
  float* bias0d = (float*)alloc(NG * 4);
  float* bias1d = (float*)alloc(NG * 4);

  (void)hipMemsetAsync(base, 0, zbytes, stream);
  const int gb = (NG * HH + 255) / 256;
  prep_weight<<<gb, 256, 0, stream>>>(eWhh0, whh0e_h, whh0e_l, 10);
  prep_weight<<<gb, 256, 0, stream>>>(eWih1, wih1e_h, wih1e_l, 10);
  prep_weight<<<gb, 256, 0, stream>>>(eWhh1, whh1e_h, whh1e_l, 10);
  prep_weight<<<gb, 256, 0, stream>>>(dWhh0, whh0d_h, whh0d_l, 10);
  prep_weight<<<gb, 256, 0, stream>>>(dWih1, wih1d_h, wih1d_l, 10);
  prep_weight<<<gb, 256, 0, stream>>>(dWhh1, whh1d_h, whh1d_l, 10);
  prep_weight<<<(NG * INF + 255) / 256, 256, 0, stream>>>(eWih0, wih0_h, wih0_l, 6);
  const int gbias = (NG + 255) / 256;
  prep_bias<<<gbias, 256, 0, stream>>>(eBih0, eBhh0, bias0e);
  prep_bias<<<gbias, 256, 0, stream>>>(eBih1, eBhh1, bias1e);
  prep_bias<<<gbias, 256, 0, stream>>>(dBih0, dBhh0, bias0d);
  prep_bias<<<gbias, 256, 0, stream>>>(dBih1, dBhh1, bias1d);
  init_out<<<(SS * BB + 255) / 256, 256, 0, stream>>>(out_tmp, fcB);

  KArgs ka;
  ka.x = x;
  ka.wih0_h = wih0_h; ka.wih0_l = wih0_l;
  ka.whh0e_h = whh0e_h; ka.whh0e_l = whh0e_l;
  ka.wih1e_h = wih1e_h; ka.wih1e_l = wih1e_l;
  ka.whh1e_h = whh1e_h; ka.whh1e_l = whh1e_l;
  ka.whh0d_h = whh0d_h; ka.whh0d_l = whh0d_l;
  ka.wih1d_h = wih1d_h; ka.wih1d_l = wih1d_l;
  ka.whh1d_h = whh1d_h; ka.whh1d_l = whh1d_l;
  ka.bias0e = bias0e; ka.bias1e = bias1e; ka.bias0d = bias0d; ka.bias1d = bias1d;
  ka.w0col = dWih0; ka.fcw = fcW; ka.fcb = fcB;
  ka.h00 = h00; ka.h01 = h01; ka.h10 = h10; ka.h11 = h11;
  ka.zb0 = zb0; ka.zb1 = zb1;
  ka.out_tmp = out_tmp;
  ka.outp = out;
  ka.arrive = bar;

  (void)hipFuncSetAttribute((const void*)seq2seq_coop,
                            hipFuncAttributeMaxDynamicSharedMemorySize, LDS_BYTES);
  seq2seq_coop<<<dim3(NBLK), dim3(NTHR), LDS_BYTES, stream>>>(ka);
}

// Round 16
// 8409.135 us; speedup vs baseline: 2.3850x; 1.2378x over previous
//
#include <hip/hip_runtime.h>
#include <cmath>
#include <cstdint>
#include <cstddef>

#define BB   128
#define TT   512
#define INF  64
#define HH   1024
#define NG   4096
#define SS   64
#define NBLK 192
#define NTHR 512   // 8 waves

// LDS: hi weights only, 4 gates x 32 kc x 64 lanes x 16B = 131072 B
#define LDS_BYTES 131072

typedef __attribute__((ext_vector_type(8))) short sh8;
typedef __attribute__((ext_vector_type(4))) float f32x4;

__device__ __forceinline__ float h2f(unsigned short u) {
  return (float)__builtin_bit_cast(_Float16, u);
}
__device__ __forceinline__ unsigned short f2h(float f) {
  return __builtin_bit_cast(unsigned short, (_Float16)f);
}
__device__ __forceinline__ float sigm(float x) { return 1.f / (1.f + __expf(-x)); }
__device__ __forceinline__ float tanh_f(float x) {
  x = fminf(15.f, fmaxf(-15.f, x));
  const float e = __expf(2.f * x);
  return (e - 1.f) / (e + 1.f);
}
__device__ __forceinline__ sh8 ld8(const unsigned short* p) { return *(const sh8*)p; }

// ---- asm accessors. sc0 sc1 = coherent (L3 coherence point, cross-XCD safe
// without fences) for mutable h/zb; plain cached for read-only weights. ----
__device__ __forceinline__ void ld8sc(sh8& d, const unsigned short* p) {
  asm volatile("global_load_dwordx4 %0, %1, off sc0 sc1" : "=v"(d) : "v"(p));
}
__device__ __forceinline__ void ldx4sc(f32x4& d, const float* p) {
  asm volatile("global_load_dwordx4 %0, %1, off sc0 sc1" : "=v"(d) : "v"(p));
}
__device__ __forceinline__ void stx4sc(float* p, f32x4 v) {
  asm volatile("global_store_dwordx4 %0, %1, off sc0 sc1" :: "v"(p), "v"(v) : "memory");
}
__device__ __forceinline__ void st16sc(unsigned short* p, unsigned int v) {
  asm volatile("global_store_short %0, %1, off sc0 sc1" :: "v"(p), "v"(v) : "memory");
}
// counted waits (rule #18: sched_barrier(0) right after stops MFMA hoisting)
__device__ __forceinline__ void waitvm(int n) {
  if (n == 6)       asm volatile("s_waitcnt vmcnt(6)" ::: "memory");
  else if (n == 4)  asm volatile("s_waitcnt vmcnt(4)" ::: "memory");
  else if (n == 2)  asm volatile("s_waitcnt vmcnt(2)" ::: "memory");
  else              asm volatile("s_waitcnt vmcnt(0)" ::: "memory");
  __builtin_amdgcn_sched_barrier(0);
}

#if defined(__HIP_DEVICE_COMPILE__)
typedef __attribute__((ext_vector_type(8))) _Float16 hf8;
template <class T> T&& my_declval();
template <class V, class = void> struct mfma_takes { static constexpr bool value = false; };
template <class V>
struct mfma_takes<V, decltype((void)__builtin_amdgcn_mfma_f32_16x16x32_f16(
                        my_declval<V>(), my_declval<V>(), my_declval<f32x4>(), 0, 0, 0))> {
  static constexpr bool value = true;
};
template <class V>
__device__ __forceinline__ f32x4 mfma_imp(V a, V b, f32x4 c) {
  return __builtin_amdgcn_mfma_f32_16x16x32_f16(a, b, c, 0, 0, 0);
}
__device__ __forceinline__ f32x4 mfma_f16(sh8 a, sh8 b, f32x4 c) {
  if constexpr (mfma_takes<sh8>::value) {
    return mfma_imp<sh8>(a, b, c);
  } else {
    return mfma_imp<hf8>(__builtin_bit_cast(hf8, a), __builtin_bit_cast(hf8, b), c);
  }
}
#else
__device__ __forceinline__ f32x4 mfma_f16(sh8, sh8, f32x4 c) { return c; }
#endif

// ---------- preprocessing ----------
// fp32 [NG][K] -> fp16 (hi only), MFMA B-fragment order.
__global__ __launch_bounds__(256) void prep_weight(const float* __restrict__ W,
                                                   unsigned short* __restrict__ hi,
                                                   int lk) {
  const int K = 1 << lk;
  const int idx = blockIdx.x * 256 + threadIdx.x;
  if (idx >= (NG << lk)) return;
  const int n = idx >> lk;
  const int k = idx & (K - 1);
  const int nkch = K >> 5;
  const size_t o =
      ((((size_t)(n >> 4) * nkch + (k >> 5)) * 64) + (((k >> 3) & 3) * 16) + (n & 15)) * 8 +
      (k & 7);
  hi[o] = f2h(W[idx]);
}

__global__ __launch_bounds__(256) void prep_bias(const float* __restrict__ a,
                                                 const float* __restrict__ b,
                                                 float* __restrict__ o) {
  const int i = blockIdx.x * 256 + threadIdx.x;
  if (i < NG) o[i] = a[i] + b[i];
}

__global__ __launch_bounds__(256) void init_out(float* __restrict__ out_tmp,
                                                const float* __restrict__ fcb) {
  const int i = blockIdx.x * 256 + threadIdx.x;
  if (i < SS * BB) out_tmp[i] = fcb[0];
}

// ---------- persistent kernel ----------
struct KArgs {
  const float* x;
  const unsigned short* wih0_h;
  const unsigned short* whh0e_h;
  const unsigned short* wih1e_h;
  const unsigned short* whh1e_h;
  const unsigned short* whh0d_h;
  const unsigned short* wih1d_h;
  const unsigned short* whh1d_h;
  const float *bias0e, *bias1e, *bias0d, *bias1d;
  const float *w0col, *fcw, *fcb;
  unsigned short *h00, *h01;  // layer-0 h ping-pong (fp16)
  unsigned short *h10, *h11;  // layer-1 h ping-pong
  float *zb0, *zb1;
  float *out_tmp;
  float *outp;
  int *arrive;  // NBLK slots, 64B apart
};

// All-to-all relaxed grid barrier (round-12-proven): data via sc0/sc1 ops
// drained by the explicit vmcnt(0); no acquire/release -> weights stay L2-warm.
__device__ __forceinline__ void gbar(int* arrive, int it) {
  asm volatile("s_waitcnt vmcnt(0)" ::: "memory");
  __syncthreads();
  const int tid = threadIdx.x;
  if (tid == 0)
    __hip_atomic_store(&arrive[blockIdx.x * 16], it, __ATOMIC_RELAXED, __HIP_MEMORY_SCOPE_AGENT);
  if (tid < NBLK) {
    while (__hip_atomic_load(&arrive[tid * 16], __ATOMIC_RELAXED, __HIP_MEMORY_SCOPE_AGENT) < it)
      __builtin_amdgcn_s_sleep(1);
  }
  __syncthreads();
  asm volatile("" ::: "memory");
}

// hi-weight slice (4 x 32KB contiguous) -> LDS (cached; read-only data)
__device__ __forceinline__ void load_whi(unsigned short* lds, const unsigned short* hi, int jt) {
#pragma unroll
  for (int g = 0; g < 4; ++g) {
    const uint4* src = (const uint4*)(hi + ((size_t)(g * 64 + jt) * 32) * 512);
    uint4* dst = (uint4*)(lds + g * 16384);
    for (int u = threadIdx.x; u < 2048; u += NTHR) dst[u] = src[u];
  }
}

// issue chunk c: 2 coherent A-fragment loads (per-wave private, no LDS)
__device__ __forceinline__ void issue_chunk(const unsigned short* arh, int c, int kg,
                                            sh8 (&AH)[2]) {
#pragma unroll
  for (int kcl = 0; kcl < 2; ++kcl)
    ld8sc(AH[kcl], arh + c * 64 + kcl * 32 + kg * 8);
}

// one K-chunk: 8 MFMA; B-hi from resident read-only LDS
__device__ __forceinline__ void compute_chunk(f32x4* acc, const unsigned short* lds, int c,
                                              int lane, const sh8 (&AH)[2]) {
  __builtin_amdgcn_s_setprio(1);
#pragma unroll
  for (int kcl = 0; kcl < 2; ++kcl) {
    const int kc = c * 2 + kcl;
#pragma unroll
    for (int g = 0; g < 4; ++g) {
      const sh8 bH = ld8(lds + (g * 32 + kc) * 512 + lane * 8);
      acc[g] = mfma_f16(AH[kcl], bH, acc[g]);
    }
  }
  __builtin_amdgcn_s_setprio(0);
}

// acc += A(fp16)[128xHH] x B(jt-slice)^T. WAVE-AUTONOMOUS (zero barriers):
// B-hi LDS is read-only after init; A prefetched 4 chunks deep per wave with
// counted vmcnt (8 ops in flight; wait 6/4/2/0 retires exactly one chunk).
__device__ __forceinline__ void gemm1024(f32x4* acc,
                                         const unsigned short* __restrict__ ah,
                                         const unsigned short* lds) {
  const int tid = threadIdx.x;
  const int lane = tid & 63, wid = tid >> 6;
  const int kg = lane >> 4;
  const int arow = wid * 16 + (lane & 15);
  const unsigned short* arh = ah + (size_t)arow * HH;

  sh8 AH[4][2];

  asm volatile("s_waitcnt vmcnt(0)" ::: "memory");  // clean vmcnt baseline
  issue_chunk(arh, 0, kg, AH[0]);
  issue_chunk(arh, 1, kg, AH[1]);
  issue_chunk(arh, 2, kg, AH[2]);
  issue_chunk(arh, 3, kg, AH[3]);

#pragma unroll
  for (int c = 0; c < 16; ++c) {
    const int rem = (c + 3 < 16) ? 3 : (15 - c);
    waitvm(rem * 2);  // chunk c's 2 loads retired
    compute_chunk(acc, lds, c, lane, AH[c % 4]);
    if (c + 4 < 16) issue_chunk(arh, c + 4, kg, AH[c % 4]);
  }
}

// encoder L0 extra: x(fp32) x Wih0, K=64; W fp16 (hi), x split hi+lo (both
// terms feed acc; x-lo residual is representable fp16 for |x| >~ 0.25).
__device__ __forceinline__ void gemm_x(f32x4* acc, const float* __restrict__ x, int t,
                                       const unsigned short* __restrict__ wxh, int jt) {
  const int tid = threadIdx.x;
  const int lane = tid & 63, wid = tid >> 6;
  const int kg = lane >> 4;
  const int arow = wid * 16 + (lane & 15);
  const float* xr = x + (size_t)arow * (TT * INF) + t * INF;
#pragma unroll
  for (int kc2 = 0; kc2 < 2; ++kc2) {
    const int kb = kc2 * 32 + kg * 8;
    sh8 xh, xl;
#pragma unroll
    for (int e = 0; e < 8; ++e) {
      const float v = xr[kb + e];
      const unsigned short h = f2h(v);
      xh[e] = (short)h;
      xl[e] = (short)f2h(v - h2f(h));
    }
#pragma unroll
    for (int g = 0; g < 4; ++g) {
      const size_t bo = (((size_t)(g * 64 + jt) * 2 + kc2) * 64 + lane) * 8;
      const sh8 bH = ld8(wxh + bo);
      acc[g] = mfma_f16(xh, bH, acc[g]);
      acc[g] = mfma_f16(xl, bH, acc[g]);
    }
  }
}

__device__ __forceinline__ void store_z(f32x4* acc, float* zb, int jt) {
  const int tid = threadIdx.x;
  const int lane = tid & 63, wid = tid >> 6;
  const int col = lane & 15, kg = lane >> 4;
#pragma unroll
  for (int g = 0; g < 4; ++g) {
    const int row = g * HH + jt * 16 + col;
    const int bq = wid * 16 + kg * 4;
    stx4sc(zb + (size_t)row * BB + bq, acc[g]);
  }
}
__device__ __forceinline__ void add_z(f32x4* acc, const float* zb, int jt) {
  const int tid = threadIdx.x;
  const int lane = tid & 63, wid = tid >> 6;
  const int col = lane & 15, kg = lane >> 4;
  f32x4 t0, t1, t2, t3;
  const int bq = wid * 16 + kg * 4;
  ldx4sc(t0, zb + (size_t)(0 * HH + jt * 16 + col) * BB + bq);
  ldx4sc(t1, zb + (size_t)(1 * HH + jt * 16 + col) * BB + bq);
  ldx4sc(t2, zb + (size_t)(2 * HH + jt * 16 + col) * BB + bq);
  ldx4sc(t3, zb + (size_t)(3 * HH + jt * 16 + col) * BB + bq);
  asm volatile("s_waitcnt vmcnt(0)" ::: "memory");
  __builtin_amdgcn_sched_barrier(0);
  acc[0] += t0;
  acc[1] += t1;
  acc[2] += t2;
  acc[3] += t3;
}

// MODE: 0 plain, 1 rank-1 decoder input, 2 FC partial output
template <int MODE>
__device__ __forceinline__ void cellfin(f32x4* acc, float* creg,
                                        const float* __restrict__ bias, int jt,
                                        unsigned short* __restrict__ nh,
                                        const float* w0g, const float* inp_vec, float fcwj,
                                        float* fc_out) {
  const int tid = threadIdx.x;
  const int lane = tid & 63, wid = tid >> 6;
  const int col = lane & 15, kg = lane >> 4;
  const int j = jt * 16 + col;
  const float b0 = bias[j], b1 = bias[HH + j], b2 = bias[2 * HH + j], b3 = bias[3 * HH + j];
#pragma unroll
  for (int r = 0; r < 4; ++r) {
    const int b = wid * 16 + kg * 4 + r;
    float zi = acc[0][r] + b0;
    float zf = acc[1][r] + b1;
    float zg = acc[2][r] + b2;
    float zo = acc[3][r] + b3;
    if constexpr (MODE == 1) {
      const float ip = inp_vec
          ? __hip_atomic_load(inp_vec + b, __ATOMIC_RELAXED, __HIP_MEMORY_SCOPE_AGENT)
          : 0.f;
      zi += ip * w0g[0];
      zf += ip * w0g[1];
      zg += ip * w0g[2];
      zo += ip * w0g[3];
    }
    const float cn = sigm(zf) * creg[r] + sigm(zi) * tanh_f(zg);
    const float hn = sigm(zo) * tanh_f(cn);
    creg[r] = cn;
    st16sc(nh + (size_t)b * HH + j, f2h(hn));  // h stored as single fp16
    if constexpr (MODE == 2) {
      float cb = hn * fcwj;
      cb += __shfl_xor(cb, 1);
      cb += __shfl_xor(cb, 2);
      cb += __shfl_xor(cb, 4);
      cb += __shfl_xor(cb, 8);
      if (col == 0) atomicAdd(fc_out + b, cb);
    }
  }
}

__device__ __forceinline__ void zacc(f32x4* acc) {
#pragma unroll
  for (int g = 0; g < 4; ++g) acc[g] = f32x4{0.f, 0.f, 0.f, 0.f};
}

__global__ __launch_bounds__(NTHR, 2) void seq2seq_coop(KArgs a) {
  extern __shared__ unsigned short lds[];
  const int bid = blockIdx.x;
  const int role = bid >> 6;
  const int jt = bid & 63;
  const int tid = threadIdx.x;
  int bseq = 0;

  unsigned short* h0[2] = {a.h00, a.h01};
  unsigned short* h1[2] = {a.h10, a.h11};
  float* zb[2] = {a.zb0, a.zb1};

  if (role == 0) load_whi(lds, a.whh0e_h, jt);
  else if (role == 1) load_whi(lds, a.wih1e_h, jt);
  else load_whi(lds, a.whh1e_h, jt);
  __syncthreads();

  float creg[4] = {};

  // ---- encoder: software-pipelined roles, 1 grid barrier per iteration ----
  for (int i = 0; i < TT + 2; ++i) {
    if (role == 0) {
      if (i < TT) {
        f32x4 acc[4];
        zacc(acc);
        gemm1024(acc, h0[(i + 1) & 1], lds);
        gemm_x(acc, a.x, i, a.wih0_h, jt);
        cellfin<0>(acc, creg, a.bias0e, jt, h0[i & 1], nullptr, nullptr, 0.f, nullptr);
      }
    } else if (role == 1) {
      if (i >= 1 && i <= TT) {
        const int s = i - 1;
        f32x4 acc[4];
        zacc(acc);
        gemm1024(acc, h0[s & 1], lds);
        store_z(acc, zb[s & 1], jt);
      }
    } else {
      if (i >= 2) {
        const int s = i - 2;
        f32x4 acc[4];
        zacc(acc);
        gemm1024(acc, h1[(s + 1) & 1], lds);
        add_z(acc, zb[s & 1], jt);
        cellfin<0>(acc, creg, a.bias1e, jt, h1[s & 1], nullptr, nullptr, 0.f, nullptr);
      }
    }
    gbar(a.arrive, ++bseq);
  }

  // ---- decoder: reload LDS weights ----
  if (role == 0) load_whi(lds, a.whh0d_h, jt);
  else if (role == 1) load_whi(lds, a.wih1d_h, jt);
  else load_whi(lds, a.whh1d_h, jt);
  __syncthreads();

  float w0g[4] = {0.f, 0.f, 0.f, 0.f};
  float fcwj = 0.f;
  if (role == 0) {
    const int j = jt * 16 + (tid & 15);
    w0g[0] = a.w0col[j];
    w0g[1] = a.w0col[HH + j];
    w0g[2] = a.w0col[2 * HH + j];
    w0g[3] = a.w0col[3 * HH + j];
  }
  if (role == 2) fcwj = a.fcw[jt * 16 + (tid & 15)];

  for (int s = 0; s < SS; ++s) {
    f32x4 acc2[4];
    if (role == 2) {
      zacc(acc2);
      gemm1024(acc2, h1[(s + 1) & 1], lds);
    }
    if (role == 0) {
      f32x4 acc[4];
      zacc(acc);
      gemm1024(acc, h0[(s + 1) & 1], lds);
      cellfin<1>(acc, creg, a.bias0d, jt, h0[s & 1], w0g,
                 s ? a.out_tmp + (s - 1) * BB : nullptr, 0.f, nullptr);
    }
    gbar(a.arrive, ++bseq);
    if (role == 1) {
      f32x4 acc[4];
      zacc(acc);
      gemm1024(acc, h0[s & 1], lds);
      store_z(acc, zb[0], jt);
    }
    gbar(a.arrive, ++bseq);
    if (role == 2) {
      add_z(acc2, zb[0], jt);
      cellfin<2>(acc2, creg, a.bias1d, jt, h1[s & 1], nullptr, nullptr, fcwj,
                 a.out_tmp + s * BB);
    }
    gbar(a.arrive, ++bseq);
  }

  // ---- final: out_tmp (S,B) -> d_out (B,S) ----
  if (bid < 16) {
    const int gi = bid * NTHR + tid;  // gi = b*64 + s
    const int b = gi >> 6, s2 = gi & 63;
    a.outp[gi] =
        __hip_atomic_load(a.out_tmp + s2 * BB + b, __ATOMIC_RELAXED, __HIP_MEMORY_SCOPE_AGENT);
  }
}

extern "C" void kernel_launch(void* const* d_in, const int* in_sizes, int n_in,
                              void* d_out, int out_size, void* d_ws, size_t ws_size,
                              hipStream_t stream) {
  (void)in_sizes; (void)n_in; (void)out_size; (void)ws_size;
  const float* x     = (const float*)d_in[0];
  const float* eWih0 = (const float*)d_in[1];
  const float* eWhh0 = (const float*)d_in[2];
  const float* eBih0 = (const float*)d_in[3];
  const float* eBhh0 = (const float*)d_in[4];
  const float* eWih1 = (const float*)d_in[5];
  const float* eWhh1 = (const float*)d_in[6];
  const float* eBih1 = (const float*)d_in[7];
  const float* eBhh1 = (const float*)d_in[8];
  const float* dWih0 = (const float*)d_in[9];
  const float* dWhh0 = (const float*)d_in[10];
  const float* dBih0 = (const float*)d_in[11];
  const float* dBhh0 = (const float*)d_in[12];
  const float* dWih1 = (const float*)d_in[13];
  const float* dWhh1 = (const float*)d_in[14];
  const float* dBih1 = (const float*)d_in[15];
  const float* dBhh1 = (const float*)d_in[16];
  const float* fcW   = (const float*)d_in[17];
  const float* fcB   = (const float*)d_in[18];
  float* out = (float*)d_out;

  char* base = (char*)d_ws;
  size_t off = 0;
  auto alloc = [&](size_t bytes) -> void* {
    void* p = base + off;
    off = (off + bytes + 255) & ~(size_t)255;
    return p;
  };

  // zero-initialized block (one memset): h buffers + barrier flags
  unsigned short* h00 = (unsigned short*)alloc(BB * HH * 2);
  unsigned short* h01 = (unsigned short*)alloc(BB * HH * 2);
  unsigned short* h10 = (unsigned short*)alloc(BB * HH * 2);
  unsigned short* h11 = (unsigned short*)alloc(BB * HH * 2);
  int* bar = (int*)alloc(NBLK * 16 * sizeof(int));
  const size_t zbytes = off;

  float* zb0 = (float*)alloc((size_t)NG * BB * 4);
  float* zb1 = (float*)alloc((size_t)NG * BB * 4);
  float* out_tmp = (float*)alloc(SS * BB * 4);

  unsigned short* wih0_h = (unsigned short*)alloc((size_t)NG * INF * 2);
  auto big = [&]() { return (unsigned short*)alloc((size_t)NG * HH * 2); };
  unsigned short* whh0e_h = big();
  unsigned short* wih1e_h = big();
  unsigned short* whh1e_h = big();
  unsigned short* whh0d_h = big();
  unsigned short* wih1d_h = big();
  unsigned short* whh1d_h = big();
  float* bias0e = (float*)alloc(NG * 4);
  float* bias1e = (float*)alloc(NG * 4);
  float* bias0d = (float*)alloc(NG * 4);
  float* bias1d = (float*)alloc(NG * 4);

  (void)hipMemsetAsync(base, 0, zbytes, stream);
  const int gb = (NG * HH + 255) / 256;
  prep_weight<<<gb, 256, 0, stream>>>(eWhh0, whh0e_h, 10);
  prep_weight<<<gb, 256, 0, stream>>>(eWih1, wih1e_h, 10);
  prep_weight<<<gb, 256, 0, stream>>>(eWhh1, whh1e_h, 10);
  prep_weight<<<gb, 256, 0, stream>>>(dWhh0, whh0d_h, 10);
  prep_weight<<<gb, 256, 0, stream>>>(dWih1, wih1d_h, 10);
  prep_weight<<<gb, 256, 0, stream>>>(dWhh1, whh1d_h, 10);
  prep_weight<<<(NG * INF + 255) / 256, 256, 0, stream>>>(eWih0, wih0_h, 6);
  const int gbias = (NG + 255) / 256;
  prep_bias<<<gbias, 256, 0, stream>>>(eBih0, eBhh0, bias0e);
  prep_bias<<<gbias, 256, 0, stream>>>(eBih1, eBhh1, bias1e);
  prep_bias<<<gbias, 256, 0, stream>>>(dBih0, dBhh0, bias0d);
  prep_bias<<<gbias, 256, 0, stream>>>(dBih1, dBhh1, bias1d);
  init_out<<<(SS * BB + 255) / 256, 256, 0, stream>>>(out_tmp, fcB);

  KArgs ka;
  ka.x = x;
  ka.wih0_h = wih0_h;
  ka.whh0e_h = whh0e_h;
  ka.wih1e_h = wih1e_h;
  ka.whh1e_h = whh1e_h;
  ka.whh0d_h = whh0d_h;
  ka.wih1d_h = wih1d_h;
  ka.whh1d_h = whh1d_h;
  ka.bias0e = bias0e; ka.bias1e = bias1e; ka.bias0d = bias0d; ka.bias1d = bias1d;
  ka.w0col = dWih0; ka.fcw = fcW; ka.fcb = fcB;
  ka.h00 = h00; ka.h01 = h01; ka.h10 = h10; ka.h11 = h11;
  ka.zb0 = zb0; ka.zb1 = zb1;
  ka.out_tmp = out_tmp;
  ka.outp = out;
  ka.arrive = bar;

  (void)hipFuncSetAttribute((const void*)seq2seq_coop,
                            hipFuncAttributeMaxDynamicSharedMemorySize, LDS_BYTES);
  seq2seq_coop<<<dim3(NBLK), dim3(NTHR), LDS_BYTES, stream>>>(ka);
}